// Round 7
// baseline (401.186 us; speedup 1.0000x reference)
//
#include <hip/hip_runtime.h>

#define HW 16384
#define CC 192
#define C3 576
#define NB 8
#define NH 8

typedef __attribute__((ext_vector_type(8))) short bfrag;
typedef __attribute__((ext_vector_type(4))) float f32x4;
typedef __attribute__((ext_vector_type(4))) unsigned short us4;

#define MFMA16(a, b, c) __builtin_amdgcn_mfma_f32_16x16x32_bf16(a, b, c, 0, 0, 0)

__device__ __forceinline__ unsigned short f2bf(float f) {
  unsigned int u = __float_as_uint(f);
  u += 0x7fffu + ((u >> 16) & 1u);
  return (unsigned short)(u >> 16);
}
__device__ __forceinline__ float bf2f(unsigned short s) {
  return __uint_as_float(((unsigned int)s) << 16);
}
__device__ __forceinline__ float bf2f_s(short s) {
  return __uint_as_float(((unsigned int)(unsigned short)s) << 16);
}

// ---------------- workspace layout (bytes) ----------------
#define OFF_XT   0ull
#define SZ_XT    ((size_t)NB * HW * CC * 2)      // x transposed bf16 [b][hw][192]; later reused as VT
#define OFF_WQ   (OFF_XT + SZ_XT)
#define SZ_WQ    ((size_t)C3 * CC * 2)           // w_qkv bf16 [576][192]
#define OFF_QKV  (OFF_WQ + SZ_WQ)
#define SZ_QKV   ((size_t)NB * C3 * HW * 2)      // qkv (pre-dw) bf16 [b][576][hw]
#define OFF_QKVD (OFF_QKV + SZ_QKV)
#define SZ_QKVD  ((size_t)NB * C3 * HW * 2)      // qkv (post-dw) bf16
#define OFF_S    (OFF_QKVD + SZ_QKVD)
#define SZ_S     ((size_t)NB * NH * 32 * 32 * 4) // gram fp32 [b][h][32][32]
#define OFF_SSQ  (OFF_S + SZ_S)
#define SZ_SSQ   ((size_t)NB * 384 * 4)          // sumsq fp32 [b][q:192 | k:192]
#define OFF_M    (OFF_SSQ + SZ_SSQ)
#define SZ_M     ((size_t)NB * CC * CC * 2)      // fused proj*attn bf16 [b][192][192]

// ---------------- prep: x -> bf16 transposed [b][hw][c] ----------------
__global__ __launch_bounds__(256) void k_xt(const float* __restrict__ x,
                                            unsigned short* __restrict__ xt) {
  __shared__ unsigned short tile[64 * 72];
  const int pb = blockIdx.x * 64;
  const int cb = blockIdx.y * 64;
  const int b  = blockIdx.z;
  const int t  = threadIdx.x;
  {
    const int cl = t >> 2, pl = (t & 3) * 16;
    const float* src = x + ((size_t)b * CC + cb + cl) * HW + pb + pl;
    bfrag v0, v1;
#pragma unroll
    for (int q4 = 0; q4 < 2; ++q4) {
      float4 f = *reinterpret_cast<const float4*>(src + q4 * 4);
      v0[q4 * 4 + 0] = (short)f2bf(f.x); v0[q4 * 4 + 1] = (short)f2bf(f.y);
      v0[q4 * 4 + 2] = (short)f2bf(f.z); v0[q4 * 4 + 3] = (short)f2bf(f.w);
    }
#pragma unroll
    for (int q4 = 0; q4 < 2; ++q4) {
      float4 f = *reinterpret_cast<const float4*>(src + 8 + q4 * 4);
      v1[q4 * 4 + 0] = (short)f2bf(f.x); v1[q4 * 4 + 1] = (short)f2bf(f.y);
      v1[q4 * 4 + 2] = (short)f2bf(f.z); v1[q4 * 4 + 3] = (short)f2bf(f.w);
    }
    *reinterpret_cast<bfrag*>(&tile[cl * 72 + pl]) = v0;
    *reinterpret_cast<bfrag*>(&tile[cl * 72 + pl + 8]) = v1;
  }
  __syncthreads();
  {
    const int pl = t >> 2, cl = (t & 3) * 16;
    bfrag o0, o1;
#pragma unroll
    for (int e = 0; e < 8; ++e) o0[e] = (short)tile[(cl + e) * 72 + pl];
#pragma unroll
    for (int e = 0; e < 8; ++e) o1[e] = (short)tile[(cl + 8 + e) * 72 + pl];
    unsigned short* dst = xt + ((size_t)b * HW + pb + pl) * CC + cb + cl;
    *reinterpret_cast<bfrag*>(dst) = o0;
    *reinterpret_cast<bfrag*>(dst + 8) = o1;
  }
}

// ---------------- prep: fp32 -> bf16 flat ----------------
__global__ void k_cvt(const float* __restrict__ in, unsigned short* __restrict__ out, int n4) {
  int i = blockIdx.x * 256 + threadIdx.x;
  if (i < n4) {
    float4 f = *reinterpret_cast<const float4*>(in + (size_t)i * 4);
    us4 o;
    o[0] = f2bf(f.x); o[1] = f2bf(f.y); o[2] = f2bf(f.z); o[3] = f2bf(f.w);
    *reinterpret_cast<us4*>(out + (size_t)i * 4) = o;
  }
}

// ---------------- qkv GEMM: Y[b][o][hw] = sum_c W[o][c] * X[b][c][hw] ----------------
// No LDS, no barriers. Block = 64 och x 2048 px (16 subtiles of 128).
// B-frags (Xt, L3/L2-resident) and A-frags (W, L2-resident) streamed to regs.
// Swapped MFMA -> D[px][ch]; direct 8B packed stores; each output row gets a
// dense 4KB run per block (DRAM page locality fix).
__global__ __launch_bounds__(256, 2) void k_gemm_qkv(const unsigned short* __restrict__ Wq,
                                                     const unsigned short* __restrict__ Xt,
                                                     unsigned short* __restrict__ Y) {
  const int pxt = blockIdx.x;  // 8 px-tiles of 2048
  const int mb  = blockIdx.y;  // 9 och-tiles of 64
  const int b   = blockIdx.z;
  const int tid = threadIdx.x;
  const int wave = tid >> 6, lane = tid & 63;
  const int lrow = lane & 15, lk = (lane >> 4) * 8, lr4 = (lane >> 4) * 4;

  const unsigned short* Xb = Xt + ((size_t)b * HW + (size_t)pxt * 2048) * CC;
  const unsigned short* Wb = Wq + (size_t)mb * 64 * CC;
  unsigned short* Yb = Y + ((size_t)b * C3 + (size_t)mb * 64) * HW + (size_t)pxt * 2048;
  const f32x4 z4 = {0.f, 0.f, 0.f, 0.f};

#pragma unroll 1
  for (int sub = 0; sub < 16; ++sub) {
    const int pxbase = sub * 128 + wave * 32;
    // B-operand (A-slot): X px-rows, k = ch contiguous. 12 x 16B gathers.
    bfrag bf[2][6];
#pragma unroll
    for (int j = 0; j < 2; ++j)
#pragma unroll
      for (int s = 0; s < 6; ++s)
        bf[j][s] = *reinterpret_cast<const bfrag*>(
            Xb + (size_t)(pxbase + j * 16 + lrow) * CC + s * 32 + lk);

    f32x4 acc[4][2];
#pragma unroll
    for (int i = 0; i < 4; ++i) { acc[i][0] = z4; acc[i][1] = z4; }

#pragma unroll
    for (int s = 0; s < 6; ++s) {
      bfrag af[4];
#pragma unroll
      for (int i = 0; i < 4; ++i)
        af[i] = *reinterpret_cast<const bfrag*>(
            Wb + (size_t)(i * 16 + lrow) * CC + s * 32 + lk);
#pragma unroll
      for (int i = 0; i < 4; ++i) {
        acc[i][0] = MFMA16(bf[0][s], af[i], acc[i][0]);  // D[px][ch]
        acc[i][1] = MFMA16(bf[1][s], af[i], acc[i][1]);
      }
    }
    // lane -> 4 consecutive px at ch = i*16+lrow
#pragma unroll
    for (int i = 0; i < 4; ++i) {
      unsigned short* rp = Yb + (size_t)(i * 16 + lrow) * HW + pxbase;
#pragma unroll
      for (int j = 0; j < 2; ++j) {
        uint2 pk;
        pk.x = (unsigned int)f2bf(acc[i][j][0]) | ((unsigned int)f2bf(acc[i][j][1]) << 16);
        pk.y = (unsigned int)f2bf(acc[i][j][2]) | ((unsigned int)f2bf(acc[i][j][3]) << 16);
        *reinterpret_cast<uint2*>(rp + j * 16 + lr4) = pk;
      }
    }
  }
}

// ---------------- depthwise 3x3 SAME ----------------
__global__ __launch_bounds__(256) void k_dwconv(const unsigned short* __restrict__ in,
                                                const float* __restrict__ wd,
                                                unsigned short* __restrict__ outb) {
  const int strip = blockIdx.x;  // 8 strips of 2048 px
  const int ch = blockIdx.y;     // 576
  const int b = blockIdx.z;
  const int t = threadIdx.x;
  const unsigned short* ip = in + ((size_t)b * C3 + ch) * HW;
  const float* w = wd + ch * 9;
  const int p = strip * 2048 + t * 8;
  const int y = p >> 7, x0 = p & 127;
  float acc[8] = {0.f, 0.f, 0.f, 0.f, 0.f, 0.f, 0.f, 0.f};
#pragma unroll
  for (int dy = 0; dy < 3; ++dy) {
    int yy = y + dy - 1;
    if (yy < 0 || yy > 127) continue;
    const unsigned short* row = ip + yy * 128;
    bfrag v = *reinterpret_cast<const bfrag*>(row + x0);
    float c[8];
#pragma unroll
    for (int e = 0; e < 8; ++e) c[e] = bf2f_s(v[e]);
    float left  = (x0 > 0)   ? bf2f(row[x0 - 1]) : 0.f;
    float right = (x0 < 120) ? bf2f(row[x0 + 8]) : 0.f;
    float wl = w[dy * 3 + 0], wc = w[dy * 3 + 1], wr = w[dy * 3 + 2];
    acc[0] += wl * left + wc * c[0] + wr * c[1];
#pragma unroll
    for (int e = 1; e < 7; ++e) acc[e] += wl * c[e - 1] + wc * c[e] + wr * c[e + 1];
    acc[7] += wl * c[6] + wc * c[7] + wr * right;
  }
  unsigned short* op = outb + ((size_t)b * C3 + ch) * HW + p;
  bfrag o;
#pragma unroll
  for (int e = 0; e < 8; ++e) o[e] = (short)f2bf(acc[e]);
  *reinterpret_cast<bfrag*>(op) = o;
}

// ---------------- transpose v part: QKVD[b][384+c][hw] -> VT[b][hw][192] ----------------
__global__ __launch_bounds__(256) void k_vt(const unsigned short* __restrict__ Vd,
                                            unsigned short* __restrict__ VTo) {
  __shared__ unsigned short tile[64 * 72];
  const int pb = blockIdx.x * 64, cb = blockIdx.y * 64, b = blockIdx.z;
  const int t = threadIdx.x;
  {
    const int cl = t >> 2, ps = (t & 3) * 16;
    const unsigned short* src = Vd + ((size_t)b * C3 + 384 + cb + cl) * HW + pb + ps;
    bfrag v0 = *reinterpret_cast<const bfrag*>(src);
    bfrag v1 = *reinterpret_cast<const bfrag*>(src + 8);
    *reinterpret_cast<bfrag*>(&tile[cl * 72 + ps]) = v0;
    *reinterpret_cast<bfrag*>(&tile[cl * 72 + ps + 8]) = v1;
  }
  __syncthreads();
  {
    const int pl = t >> 2, cs = (t & 3) * 16;
    bfrag o0, o1;
#pragma unroll
    for (int e = 0; e < 8; ++e) o0[e] = (short)tile[(cs + e) * 72 + pl];
#pragma unroll
    for (int e = 0; e < 8; ++e) o1[e] = (short)tile[(cs + 8 + e) * 72 + pl];
    unsigned short* dst = VTo + ((size_t)b * HW + pb + pl) * CC + cb + cs;
    *reinterpret_cast<bfrag*>(dst) = o0;
    *reinterpret_cast<bfrag*>(dst + 8) = o1;
  }
}

// ---------------- gram S[b][h][c1][c2] += q.k over pixels; ssq of q,k ----------------
__global__ __launch_bounds__(256) void k_gram(const unsigned short* __restrict__ Qd,
                                              float* __restrict__ S,
                                              float* __restrict__ ssq) {
  const int chunk = blockIdx.x;  // 16 chunks of 1024 px
  const int h = blockIdx.y, b = blockIdx.z;
  const int tid = threadIdx.x, wave = tid >> 6, lane = tid & 63;
  const int lrow = lane & 15, lk8 = (lane >> 4) * 8;
  const unsigned short* qb = Qd + ((size_t)b * C3 + h * 24) * HW;
  const unsigned short* kb = qb + (size_t)192 * HW;
  const int p0 = chunk * 1024 + wave * 256;
  f32x4 acc[2][2];
  const f32x4 z4 = {0.f, 0.f, 0.f, 0.f};
#pragma unroll
  for (int i = 0; i < 2; ++i)
#pragma unroll
    for (int j = 0; j < 2; ++j) acc[i][j] = z4;
  float sq[2] = {0.f, 0.f}, sk[2] = {0.f, 0.f};
  for (int s = 0; s < 8; ++s) {
    const int pp = p0 + s * 32 + lk8;
    bfrag aq[2], bk[2];
#pragma unroll
    for (int i = 0; i < 2; ++i) {
      aq[i] = *reinterpret_cast<const bfrag*>(qb + (size_t)(i * 16 + lrow) * HW + pp);
      bk[i] = *reinterpret_cast<const bfrag*>(kb + (size_t)(i * 16 + lrow) * HW + pp);
    }
#pragma unroll
    for (int i = 0; i < 2; ++i) {
#pragma unroll
      for (int e = 0; e < 8; ++e) {
        float qv = bf2f_s(aq[i][e]); sq[i] += qv * qv;
        float kv = bf2f_s(bk[i][e]); sk[i] += kv * kv;
      }
    }
#pragma unroll
    for (int i = 0; i < 2; ++i)
#pragma unroll
      for (int j = 0; j < 2; ++j) acc[i][j] = MFMA16(aq[i], bk[j], acc[i][j]);
  }
  float* Sb = S + (size_t)(b * 8 + h) * 1024;
  const int lr4 = (lane >> 4) * 4;
#pragma unroll
  for (int i = 0; i < 2; ++i)
#pragma unroll
    for (int j = 0; j < 2; ++j)
#pragma unroll
      for (int r = 0; r < 4; ++r)
        atomicAdd(&Sb[(i * 16 + lr4 + r) * 32 + j * 16 + lrow], acc[i][j][r]);
#pragma unroll
  for (int i = 0; i < 2; ++i) {
    float v = sq[i];
    v += __shfl_xor(v, 16); v += __shfl_xor(v, 32);
    float wv = sk[i];
    wv += __shfl_xor(wv, 16); wv += __shfl_xor(wv, 32);
    const int c = i * 16 + lrow;
    if ((lane >> 4) == 0 && c < 24) {
      atomicAdd(&ssq[b * 384 + h * 24 + c], v);
      atomicAdd(&ssq[b * 384 + 192 + h * 24 + c], wv);
    }
  }
}

// ---------------- softmax + M = wproj @ blockdiag(attn) ----------------
__global__ __launch_bounds__(64) void k_attn(const float* __restrict__ S,
                                             const float* __restrict__ ssq,
                                             const float* __restrict__ wproj,
                                             const float* __restrict__ temp,
                                             unsigned short* __restrict__ Mbf) {
  const int h = blockIdx.x, b = blockIdx.y;
  __shared__ float A[24][25];
  __shared__ float nq[24], nk[24];
  const float* Sb = S + (size_t)(b * 8 + h) * 1024;
  const float* sq = ssq + b * 384 + h * 24;
  const float* sk = ssq + b * 384 + 192 + h * 24;
  const int t = threadIdx.x;
  if (t < 24) {
    nq[t] = fmaxf(sqrtf(sq[t]), 1e-12f);
    nk[t] = fmaxf(sqrtf(sk[t]), 1e-12f);
  }
  __syncthreads();
  if (t < 24) {
    const float tp = temp[h];
    float row[24];
    float mx = -1e30f;
#pragma unroll
    for (int d = 0; d < 24; ++d) {
      row[d] = Sb[t * 32 + d] / (nq[t] * nk[d]) * tp;
      mx = fmaxf(mx, row[d]);
    }
    float s = 0.f;
#pragma unroll
    for (int d = 0; d < 24; ++d) { row[d] = __expf(row[d] - mx); s += row[d]; }
    const float inv = 1.f / s;
#pragma unroll
    for (int d = 0; d < 24; ++d) A[t][d] = row[d] * inv;
  }
  __syncthreads();
  for (int idx = t; idx < 192 * 24; idx += 64) {
    const int o = idx / 24, dd = idx % 24;
    const float* wrow = wproj + o * 192 + h * 24;
    float a = 0.f;
#pragma unroll
    for (int cc = 0; cc < 24; ++cc) a += wrow[cc] * A[cc][dd];
    Mbf[((size_t)b * 192 + o) * 192 + h * 24 + dd] = f2bf(a);
  }
}

// ---------------- out GEMM: out[b][o][hw] = sum_d M[b][o][d] * VT[b][hw][d] ----------------
// No LDS, no barriers. Block = 192 och x 512 px (4 subtiles of 128); B-frags from
// VT (L3), A-frags from M (L2). Dense 2KB write runs per fp32 output row.
__global__ __launch_bounds__(256, 2) void k_gemm_out(const unsigned short* __restrict__ M,
                                                     const unsigned short* __restrict__ VT,
                                                     float* __restrict__ out) {
  const int pxt = blockIdx.x;  // 32 px-tiles of 512
  const int b   = blockIdx.y;
  const int tid = threadIdx.x;
  const int wave = tid >> 6, lane = tid & 63;
  const int lrow = lane & 15, lk = (lane >> 4) * 8, lr4 = (lane >> 4) * 4;

  const unsigned short* Vb = VT + ((size_t)b * HW + (size_t)pxt * 512) * CC;
  const unsigned short* Mb = M + (size_t)b * CC * CC;
  float* Ob = out + (size_t)b * CC * HW + (size_t)pxt * 512;
  const f32x4 z4 = {0.f, 0.f, 0.f, 0.f};

#pragma unroll 1
  for (int sub = 0; sub < 4; ++sub) {
    const int pxbase = sub * 128 + wave * 32;
    bfrag bf[2][6];
#pragma unroll
    for (int j = 0; j < 2; ++j)
#pragma unroll
      for (int s = 0; s < 6; ++s)
        bf[j][s] = *reinterpret_cast<const bfrag*>(
            Vb + (size_t)(pxbase + j * 16 + lrow) * CC + s * 32 + lk);

#pragma unroll
    for (int mb = 0; mb < 3; ++mb) {
      f32x4 acc[4][2];
#pragma unroll
      for (int i = 0; i < 4; ++i) { acc[i][0] = z4; acc[i][1] = z4; }
#pragma unroll
      for (int s = 0; s < 6; ++s) {
        bfrag af[4];
#pragma unroll
        for (int i = 0; i < 4; ++i)
          af[i] = *reinterpret_cast<const bfrag*>(
              Mb + (size_t)(mb * 64 + i * 16 + lrow) * CC + s * 32 + lk);
#pragma unroll
        for (int i = 0; i < 4; ++i) {
          acc[i][0] = MFMA16(bf[0][s], af[i], acc[i][0]);  // D[px][ch]
          acc[i][1] = MFMA16(bf[1][s], af[i], acc[i][1]);
        }
      }
#pragma unroll
      for (int i = 0; i < 4; ++i) {
        float* rp = Ob + (size_t)(mb * 64 + i * 16 + lrow) * HW + pxbase;
#pragma unroll
        for (int j = 0; j < 2; ++j)
          *reinterpret_cast<f32x4*>(rp + j * 16 + lr4) = acc[i][j];
      }
    }
  }
}

extern "C" void kernel_launch(void* const* d_in, const int* in_sizes, int n_in,
                              void* d_out, int out_size, void* d_ws, size_t ws_size,
                              hipStream_t stream) {
  const float* x      = (const float*)d_in[0];
  const float* w_qkv  = (const float*)d_in[1];
  const float* w_dw   = (const float*)d_in[2];
  const float* w_proj = (const float*)d_in[3];
  const float* temp   = (const float*)d_in[4];
  float* out = (float*)d_out;
  char* ws = (char*)d_ws;

  unsigned short* XT   = (unsigned short*)(ws + OFF_XT);
  unsigned short* VT   = (unsigned short*)(ws + OFF_XT);  // reuse: XT dead after qkv GEMM
  unsigned short* WQ   = (unsigned short*)(ws + OFF_WQ);
  unsigned short* QKV  = (unsigned short*)(ws + OFF_QKV);
  unsigned short* QKVD = (unsigned short*)(ws + OFF_QKVD);
  float* S   = (float*)(ws + OFF_S);
  float* SSQ = (float*)(ws + OFF_SSQ);
  unsigned short* MBF = (unsigned short*)(ws + OFF_M);

  hipMemsetAsync(ws + OFF_S, 0, SZ_S + SZ_SSQ, stream);
  k_cvt<<<(C3 * CC / 4 + 255) / 256, 256, 0, stream>>>(w_qkv, WQ, C3 * CC / 4);
  k_xt<<<dim3(HW / 64, CC / 64, NB), 256, 0, stream>>>(x, XT);
  k_gemm_qkv<<<dim3(8, 9, NB), 256, 0, stream>>>(WQ, XT, QKV);
  k_dwconv<<<dim3(8, C3, NB), 256, 0, stream>>>(QKV, w_dw, QKVD);
  k_vt<<<dim3(HW / 64, 3, NB), 256, 0, stream>>>(QKVD, VT);
  k_gram<<<dim3(16, NH, NB), 256, 0, stream>>>(QKVD, S, SSQ);
  k_attn<<<dim3(NH, NB), 64, 0, stream>>>(S, SSQ, w_proj, temp, MBF);
  k_gemm_out<<<dim3(32, NB), 256, 0, stream>>>(MBF, VT, out);
}

// Round 8
// 336.363 us; speedup vs baseline: 1.1927x; 1.1927x over previous
//
#include <hip/hip_runtime.h>

#define HW 16384
#define CC 192
#define C3 576
#define NB 8
#define NH 8

typedef __attribute__((ext_vector_type(8))) short bfrag;
typedef __attribute__((ext_vector_type(4))) float f32x4;
typedef __attribute__((ext_vector_type(4))) unsigned short us4;

#define MFMA16(a, b, c) __builtin_amdgcn_mfma_f32_16x16x32_bf16(a, b, c, 0, 0, 0)

typedef __attribute__((address_space(3))) unsigned int lds_u32;
typedef __attribute__((address_space(1))) unsigned int glb_u32;
__device__ __forceinline__ void gl_lds16(const void* g, void* l) {
  __builtin_amdgcn_global_load_lds((const glb_u32*)g, (lds_u32*)l, 16, 0, 0);
}

__device__ __forceinline__ unsigned short f2bf(float f) {
  unsigned int u = __float_as_uint(f);
  u += 0x7fffu + ((u >> 16) & 1u);
  return (unsigned short)(u >> 16);
}
__device__ __forceinline__ float bf2f(unsigned short s) {
  return __uint_as_float(((unsigned int)s) << 16);
}
__device__ __forceinline__ float bf2f_s(short s) {
  return __uint_as_float(((unsigned int)(unsigned short)s) << 16);
}

// ---------------- workspace layout (bytes) ----------------
#define OFF_XT   0ull
#define SZ_XT    ((size_t)NB * HW * CC * 2)      // x transposed bf16 [b][hw][192]; later reused as VT
#define OFF_WQ   (OFF_XT + SZ_XT)
#define SZ_WQ    ((size_t)C3 * CC * 2)           // W packed into MFMA frag order
#define OFF_QKV  (OFF_WQ + SZ_WQ)
#define SZ_QKV   ((size_t)NB * C3 * HW * 2)      // qkv (pre-dw) bf16 [b][576][hw]
#define OFF_QKVD (OFF_QKV + SZ_QKV)
#define SZ_QKVD  ((size_t)NB * C3 * HW * 2)      // qkv (post-dw) bf16
#define OFF_S    (OFF_QKVD + SZ_QKVD)
#define SZ_S     ((size_t)NB * NH * 32 * 32 * 4) // gram fp32 [b][h][32][32]
#define OFF_SSQ  (OFF_S + SZ_S)
#define SZ_SSQ   ((size_t)NB * 384 * 4)          // sumsq fp32 [b][q:192 | k:192]
#define OFF_M    (OFF_SSQ + SZ_SSQ)
#define SZ_M     ((size_t)NB * CC * CC * 2)      // fused proj*attn, packed frag order

// ---------------- prep: x -> bf16 transposed [b][hw][c] ----------------
__global__ __launch_bounds__(256) void k_xt(const float* __restrict__ x,
                                            unsigned short* __restrict__ xt) {
  __shared__ unsigned short tile[64 * 72];
  const int pb = blockIdx.x * 64;
  const int cb = blockIdx.y * 64;
  const int b  = blockIdx.z;
  const int t  = threadIdx.x;
  {
    const int cl = t >> 2, pl = (t & 3) * 16;
    const float* src = x + ((size_t)b * CC + cb + cl) * HW + pb + pl;
    bfrag v0, v1;
#pragma unroll
    for (int q4 = 0; q4 < 2; ++q4) {
      float4 f = *reinterpret_cast<const float4*>(src + q4 * 4);
      v0[q4 * 4 + 0] = (short)f2bf(f.x); v0[q4 * 4 + 1] = (short)f2bf(f.y);
      v0[q4 * 4 + 2] = (short)f2bf(f.z); v0[q4 * 4 + 3] = (short)f2bf(f.w);
    }
#pragma unroll
    for (int q4 = 0; q4 < 2; ++q4) {
      float4 f = *reinterpret_cast<const float4*>(src + 8 + q4 * 4);
      v1[q4 * 4 + 0] = (short)f2bf(f.x); v1[q4 * 4 + 1] = (short)f2bf(f.y);
      v1[q4 * 4 + 2] = (short)f2bf(f.z); v1[q4 * 4 + 3] = (short)f2bf(f.w);
    }
    *reinterpret_cast<bfrag*>(&tile[cl * 72 + pl]) = v0;
    *reinterpret_cast<bfrag*>(&tile[cl * 72 + pl + 8]) = v1;
  }
  __syncthreads();
  {
    const int pl = t >> 2, cl = (t & 3) * 16;
    bfrag o0, o1;
#pragma unroll
    for (int e = 0; e < 8; ++e) o0[e] = (short)tile[(cl + e) * 72 + pl];
#pragma unroll
    for (int e = 0; e < 8; ++e) o1[e] = (short)tile[(cl + 8 + e) * 72 + pl];
    unsigned short* dst = xt + ((size_t)b * HW + pb + pl) * CC + cb + cl;
    *reinterpret_cast<bfrag*>(dst) = o0;
    *reinterpret_cast<bfrag*>(dst + 8) = o1;
  }
}

// ---------------- prep: pack W into MFMA fragment order ----------------
// Wp[((mb*24 + s*4 + i)*64 + lane)*8 + e] = W[mb*64+i*16+(lane&15)][s*32+(lane>>4)*8+e]
__global__ __launch_bounds__(256) void k_wpack(const float* __restrict__ w,
                                               unsigned short* __restrict__ wp) {
  const int g = blockIdx.x * 256 + threadIdx.x;
  if (g >= 216 * 64) return;
  const int frag = g >> 6, lane = g & 63;
  const int mb = frag / 24, r = frag % 24, s = r >> 2, i = r & 3;
  const int row = mb * 64 + i * 16 + (lane & 15);
  const int col = s * 32 + (lane >> 4) * 8;
  const float* src = w + (size_t)row * CC + col;
  float4 f0 = *reinterpret_cast<const float4*>(src);
  float4 f1 = *reinterpret_cast<const float4*>(src + 4);
  us4 o0, o1;
  o0[0] = f2bf(f0.x); o0[1] = f2bf(f0.y); o0[2] = f2bf(f0.z); o0[3] = f2bf(f0.w);
  o1[0] = f2bf(f1.x); o1[1] = f2bf(f1.y); o1[2] = f2bf(f1.z); o1[3] = f2bf(f1.w);
  *reinterpret_cast<us4*>(wp + (size_t)g * 8) = o0;
  *reinterpret_cast<us4*>(wp + (size_t)g * 8 + 4) = o1;
}

// ---------------- qkv GEMM ----------------
// B (Xt slab) staged once to LDS via global_load_lds (swizzled); A from packed Wp:
// every A-load = wave-contiguous 1KB (frag-order). Swapped MFMA -> D[px][ch],
// direct 8B packed stores, one barrier total.
__global__ __launch_bounds__(256, 3) void k_gemm_qkv(const unsigned short* __restrict__ Wp,
                                                     const unsigned short* __restrict__ Xt,
                                                     unsigned short* __restrict__ Y) {
  __shared__ __attribute__((aligned(16))) char sB[49152];
  const int nb = blockIdx.x;  // 128 px tiles of 128
  const int b  = blockIdx.y;
  const int tid = threadIdx.x;
  const int wave = tid >> 6, lane = tid & 63;
  const int lrow = lane & 15, lk = (lane >> 4) * 8, lr4 = (lane >> 4) * 4;

  const char* Bc = (const char*)(Xt + ((size_t)b * HW + (size_t)nb * 128) * CC);
#pragma unroll
  for (int t = 0; t < 12; ++t) {
    const int L = wave * 12288 + t * 1024 + lane * 16;
    const int row = L / 384;
    const int rem = L - row * 384;
    gl_lds16(Bc + row * 384 + (rem ^ ((row & 7) << 4)), sB + wave * 12288 + t * 1024);
  }
  asm volatile("s_waitcnt vmcnt(0)" ::: "memory");
  __syncthreads();

  const int swz = (lrow & 7) << 4;
  const int base0 = (wave * 32 + lrow) * 384;
  const f32x4 z4 = {0.f, 0.f, 0.f, 0.f};

#pragma unroll 1
  for (int mb = 0; mb < 9; ++mb) {
    const unsigned short* Wb = Wp + (size_t)mb * 24 * 512;
    bfrag af[6][4];
#pragma unroll
    for (int s = 0; s < 6; ++s)
#pragma unroll
      for (int i = 0; i < 4; ++i)
        af[s][i] = *reinterpret_cast<const bfrag*>(Wb + ((s * 4 + i) * 64 + lane) * 8);

    f32x4 acc[4][2];
#pragma unroll
    for (int i = 0; i < 4; ++i) { acc[i][0] = z4; acc[i][1] = z4; }
#pragma unroll
    for (int s = 0; s < 6; ++s) {
      const int kbs = ((s * 32 + lk) * 2) ^ swz;
      bfrag b0 = *reinterpret_cast<const bfrag*>(sB + base0 + kbs);
      bfrag b1 = *reinterpret_cast<const bfrag*>(sB + base0 + 16 * 384 + kbs);
#pragma unroll
      for (int i = 0; i < 4; ++i) {
        acc[i][0] = MFMA16(b0, af[s][i], acc[i][0]);  // D[px][ch]
        acc[i][1] = MFMA16(b1, af[s][i], acc[i][1]);
      }
    }
    unsigned short* Yb = Y + ((size_t)b * C3 + mb * 64) * HW + nb * 128 + wave * 32;
#pragma unroll
    for (int i = 0; i < 4; ++i) {
      unsigned short* rp = Yb + (size_t)(i * 16 + lrow) * HW;
#pragma unroll
      for (int j = 0; j < 2; ++j) {
        uint2 pk;
        pk.x = (unsigned int)f2bf(acc[i][j][0]) | ((unsigned int)f2bf(acc[i][j][1]) << 16);
        pk.y = (unsigned int)f2bf(acc[i][j][2]) | ((unsigned int)f2bf(acc[i][j][3]) << 16);
        *reinterpret_cast<uint2*>(rp + j * 16 + lr4) = pk;
      }
    }
  }
}

// ---------------- depthwise 3x3 SAME ----------------
__global__ __launch_bounds__(256) void k_dwconv(const unsigned short* __restrict__ in,
                                                const float* __restrict__ wd,
                                                unsigned short* __restrict__ outb) {
  const int strip = blockIdx.x;  // 8 strips of 2048 px
  const int ch = blockIdx.y;     // 576
  const int b = blockIdx.z;
  const int t = threadIdx.x;
  const unsigned short* ip = in + ((size_t)b * C3 + ch) * HW;
  const float* w = wd + ch * 9;
  const int p = strip * 2048 + t * 8;
  const int y = p >> 7, x0 = p & 127;
  float acc[8] = {0.f, 0.f, 0.f, 0.f, 0.f, 0.f, 0.f, 0.f};
#pragma unroll
  for (int dy = 0; dy < 3; ++dy) {
    int yy = y + dy - 1;
    if (yy < 0 || yy > 127) continue;
    const unsigned short* row = ip + yy * 128;
    bfrag v = *reinterpret_cast<const bfrag*>(row + x0);
    float c[8];
#pragma unroll
    for (int e = 0; e < 8; ++e) c[e] = bf2f_s(v[e]);
    float left  = (x0 > 0)   ? bf2f(row[x0 - 1]) : 0.f;
    float right = (x0 < 120) ? bf2f(row[x0 + 8]) : 0.f;
    float wl = w[dy * 3 + 0], wc = w[dy * 3 + 1], wr = w[dy * 3 + 2];
    acc[0] += wl * left + wc * c[0] + wr * c[1];
#pragma unroll
    for (int e = 1; e < 7; ++e) acc[e] += wl * c[e - 1] + wc * c[e] + wr * c[e + 1];
    acc[7] += wl * c[6] + wc * c[7] + wr * right;
  }
  unsigned short* op = outb + ((size_t)b * C3 + ch) * HW + p;
  bfrag o;
#pragma unroll
  for (int e = 0; e < 8; ++e) o[e] = (short)f2bf(acc[e]);
  *reinterpret_cast<bfrag*>(op) = o;
}

// ---------------- transpose v part: QKVD[b][384+c][hw] -> VT[b][hw][192] ----------------
__global__ __launch_bounds__(256) void k_vt(const unsigned short* __restrict__ Vd,
                                            unsigned short* __restrict__ VTo) {
  __shared__ unsigned short tile[64 * 72];
  const int pb = blockIdx.x * 64, cb = blockIdx.y * 64, b = blockIdx.z;
  const int t = threadIdx.x;
  {
    const int cl = t >> 2, ps = (t & 3) * 16;
    const unsigned short* src = Vd + ((size_t)b * C3 + 384 + cb + cl) * HW + pb + ps;
    bfrag v0 = *reinterpret_cast<const bfrag*>(src);
    bfrag v1 = *reinterpret_cast<const bfrag*>(src + 8);
    *reinterpret_cast<bfrag*>(&tile[cl * 72 + ps]) = v0;
    *reinterpret_cast<bfrag*>(&tile[cl * 72 + ps + 8]) = v1;
  }
  __syncthreads();
  {
    const int pl = t >> 2, cs = (t & 3) * 16;
    bfrag o0, o1;
#pragma unroll
    for (int e = 0; e < 8; ++e) o0[e] = (short)tile[(cs + e) * 72 + pl];
#pragma unroll
    for (int e = 0; e < 8; ++e) o1[e] = (short)tile[(cs + 8 + e) * 72 + pl];
    unsigned short* dst = VTo + ((size_t)b * HW + pb + pl) * CC + cb + cs;
    *reinterpret_cast<bfrag*>(dst) = o0;
    *reinterpret_cast<bfrag*>(dst + 8) = o1;
  }
}

// ---------------- gram S[b][h][c1][c2] += q.k over pixels; ssq of q,k ----------------
__global__ __launch_bounds__(256) void k_gram(const unsigned short* __restrict__ Qd,
                                              float* __restrict__ S,
                                              float* __restrict__ ssq) {
  const int chunk = blockIdx.x;  // 16 chunks of 1024 px
  const int h = blockIdx.y, b = blockIdx.z;
  const int tid = threadIdx.x, wave = tid >> 6, lane = tid & 63;
  const int lrow = lane & 15, lk8 = (lane >> 4) * 8;
  const unsigned short* qb = Qd + ((size_t)b * C3 + h * 24) * HW;
  const unsigned short* kb = qb + (size_t)192 * HW;
  const int p0 = chunk * 1024 + wave * 256;
  f32x4 acc[2][2];
  const f32x4 z4 = {0.f, 0.f, 0.f, 0.f};
#pragma unroll
  for (int i = 0; i < 2; ++i)
#pragma unroll
    for (int j = 0; j < 2; ++j) acc[i][j] = z4;
  float sq[2] = {0.f, 0.f}, sk[2] = {0.f, 0.f};
  for (int s = 0; s < 8; ++s) {
    const int pp = p0 + s * 32 + lk8;
    bfrag aq[2], bk[2];
#pragma unroll
    for (int i = 0; i < 2; ++i) {
      aq[i] = *reinterpret_cast<const bfrag*>(qb + (size_t)(i * 16 + lrow) * HW + pp);
      bk[i] = *reinterpret_cast<const bfrag*>(kb + (size_t)(i * 16 + lrow) * HW + pp);
    }
#pragma unroll
    for (int i = 0; i < 2; ++i) {
#pragma unroll
      for (int e = 0; e < 8; ++e) {
        float qv = bf2f_s(aq[i][e]); sq[i] += qv * qv;
        float kv = bf2f_s(bk[i][e]); sk[i] += kv * kv;
      }
    }
#pragma unroll
    for (int i = 0; i < 2; ++i)
#pragma unroll
      for (int j = 0; j < 2; ++j) acc[i][j] = MFMA16(aq[i], bk[j], acc[i][j]);
  }
  float* Sb = S + (size_t)(b * 8 + h) * 1024;
  const int lr4 = (lane >> 4) * 4;
#pragma unroll
  for (int i = 0; i < 2; ++i)
#pragma unroll
    for (int j = 0; j < 2; ++j)
#pragma unroll
      for (int r = 0; r < 4; ++r)
        atomicAdd(&Sb[(i * 16 + lr4 + r) * 32 + j * 16 + lrow], acc[i][j][r]);
#pragma unroll
  for (int i = 0; i < 2; ++i) {
    float v = sq[i];
    v += __shfl_xor(v, 16); v += __shfl_xor(v, 32);
    float wv = sk[i];
    wv += __shfl_xor(wv, 16); wv += __shfl_xor(wv, 32);
    const int c = i * 16 + lrow;
    if ((lane >> 4) == 0 && c < 24) {
      atomicAdd(&ssq[b * 384 + h * 24 + c], v);
      atomicAdd(&ssq[b * 384 + 192 + h * 24 + c], wv);
    }
  }
}

// ---------------- softmax + M = wproj @ blockdiag(attn), written PACKED ----------------
__global__ __launch_bounds__(64) void k_attn(const float* __restrict__ S,
                                             const float* __restrict__ ssq,
                                             const float* __restrict__ wproj,
                                             const float* __restrict__ temp,
                                             unsigned short* __restrict__ Mp) {
  const int h = blockIdx.x, b = blockIdx.y;
  __shared__ float A[24][25];
  __shared__ float nq[24], nk[24];
  const float* Sb = S + (size_t)(b * 8 + h) * 1024;
  const float* sq = ssq + b * 384 + h * 24;
  const float* sk = ssq + b * 384 + 192 + h * 24;
  const int t = threadIdx.x;
  if (t < 24) {
    nq[t] = fmaxf(sqrtf(sq[t]), 1e-12f);
    nk[t] = fmaxf(sqrtf(sk[t]), 1e-12f);
  }
  __syncthreads();
  if (t < 24) {
    const float tp = temp[h];
    float row[24];
    float mx = -1e30f;
#pragma unroll
    for (int d = 0; d < 24; ++d) {
      row[d] = Sb[t * 32 + d] / (nq[t] * nk[d]) * tp;
      mx = fmaxf(mx, row[d]);
    }
    float s = 0.f;
#pragma unroll
    for (int d = 0; d < 24; ++d) { row[d] = __expf(row[d] - mx); s += row[d]; }
    const float inv = 1.f / s;
#pragma unroll
    for (int d = 0; d < 24; ++d) A[t][d] = row[d] * inv;
  }
  __syncthreads();
  for (int idx = t; idx < 192 * 24; idx += 64) {
    const int o = idx / 24, dd = idx % 24;
    const float* wrow = wproj + o * 192 + h * 24;
    float a = 0.f;
#pragma unroll
    for (int cc = 0; cc < 24; ++cc) a += wrow[cc] * A[cc][dd];
    // packed fragment index for M[o][c], c = h*24+dd
    const int c = h * 24 + dd;
    const int mb = o >> 6, i = (o >> 4) & 3, lr = o & 15;
    const int s = c >> 5, hi = (c >> 3) & 3, e = c & 7;
    const int off = ((mb * 24 + s * 4 + i) * 64 + hi * 16 + lr) * 8 + e;
    Mp[(size_t)b * CC * CC + off] = f2bf(a);
  }
}

// ---------------- out GEMM: out[b][o][hw] = sum_d M[b][o][d] * VT[b][hw][d] ----------------
// Same structure as k_gemm_qkv: staged B, packed M frags, swapped MFMA,
// fp32 16B stores (full 64B lines per wave-instruction).
__global__ __launch_bounds__(256, 3) void k_gemm_out(const unsigned short* __restrict__ Mp,
                                                     const unsigned short* __restrict__ VT,
                                                     float* __restrict__ out) {
  __shared__ __attribute__((aligned(16))) char sB[49152];
  const int nb = blockIdx.x;  // 128 px tiles of 128
  const int b  = blockIdx.y;
  const int tid = threadIdx.x;
  const int wave = tid >> 6, lane = tid & 63;
  const int lrow = lane & 15, lk = (lane >> 4) * 8, lr4 = (lane >> 4) * 4;

  const char* Bc = (const char*)(VT + ((size_t)b * HW + (size_t)nb * 128) * CC);
#pragma unroll
  for (int t = 0; t < 12; ++t) {
    const int L = wave * 12288 + t * 1024 + lane * 16;
    const int row = L / 384;
    const int rem = L - row * 384;
    gl_lds16(Bc + row * 384 + (rem ^ ((row & 7) << 4)), sB + wave * 12288 + t * 1024);
  }
  asm volatile("s_waitcnt vmcnt(0)" ::: "memory");
  __syncthreads();

  const int swz = (lrow & 7) << 4;
  const int base0 = (wave * 32 + lrow) * 384;
  const f32x4 z4 = {0.f, 0.f, 0.f, 0.f};

#pragma unroll 1
  for (int mb = 0; mb < 3; ++mb) {
    const unsigned short* Mb = Mp + (size_t)b * CC * CC + (size_t)mb * 24 * 512;
    bfrag af[6][4];
#pragma unroll
    for (int s = 0; s < 6; ++s)
#pragma unroll
      for (int i = 0; i < 4; ++i)
        af[s][i] = *reinterpret_cast<const bfrag*>(Mb + ((s * 4 + i) * 64 + lane) * 8);

    f32x4 acc[4][2];
#pragma unroll
    for (int i = 0; i < 4; ++i) { acc[i][0] = z4; acc[i][1] = z4; }
#pragma unroll
    for (int s = 0; s < 6; ++s) {
      const int kbs = ((s * 32 + lk) * 2) ^ swz;
      bfrag b0 = *reinterpret_cast<const bfrag*>(sB + base0 + kbs);
      bfrag b1 = *reinterpret_cast<const bfrag*>(sB + base0 + 16 * 384 + kbs);
#pragma unroll
      for (int i = 0; i < 4; ++i) {
        acc[i][0] = MFMA16(b0, af[s][i], acc[i][0]);  // D[px][ch]
        acc[i][1] = MFMA16(b1, af[s][i], acc[i][1]);
      }
    }
    float* Ob = out + ((size_t)b * CC + mb * 64) * HW + nb * 128 + wave * 32;
#pragma unroll
    for (int i = 0; i < 4; ++i) {
      float* rp = Ob + (size_t)(i * 16 + lrow) * HW;
#pragma unroll
      for (int j = 0; j < 2; ++j)
        *reinterpret_cast<f32x4*>(rp + j * 16 + lr4) = acc[i][j];
    }
  }
}

extern "C" void kernel_launch(void* const* d_in, const int* in_sizes, int n_in,
                              void* d_out, int out_size, void* d_ws, size_t ws_size,
                              hipStream_t stream) {
  const float* x      = (const float*)d_in[0];
  const float* w_qkv  = (const float*)d_in[1];
  const float* w_dw   = (const float*)d_in[2];
  const float* w_proj = (const float*)d_in[3];
  const float* temp   = (const float*)d_in[4];
  float* out = (float*)d_out;
  char* ws = (char*)d_ws;

  unsigned short* XT   = (unsigned short*)(ws + OFF_XT);
  unsigned short* VT   = (unsigned short*)(ws + OFF_XT);  // reuse: XT dead after qkv GEMM
  unsigned short* WP   = (unsigned short*)(ws + OFF_WQ);
  unsigned short* QKV  = (unsigned short*)(ws + OFF_QKV);
  unsigned short* QKVD = (unsigned short*)(ws + OFF_QKVD);
  float* S   = (float*)(ws + OFF_S);
  float* SSQ = (float*)(ws + OFF_SSQ);
  unsigned short* MP  = (unsigned short*)(ws + OFF_M);

  hipMemsetAsync(ws + OFF_S, 0, SZ_S + SZ_SSQ, stream);
  k_wpack<<<54, 256, 0, stream>>>(w_qkv, WP);
  k_xt<<<dim3(HW / 64, CC / 64, NB), 256, 0, stream>>>(x, XT);
  k_gemm_qkv<<<dim3(HW / 128, NB), 256, 0, stream>>>(WP, XT, QKV);
  k_dwconv<<<dim3(8, C3, NB), 256, 0, stream>>>(QKV, w_dw, QKVD);
  k_vt<<<dim3(HW / 64, 3, NB), 256, 0, stream>>>(QKVD, VT);
  k_gram<<<dim3(16, NH, NB), 256, 0, stream>>>(QKVD, S, SSQ);
  k_attn<<<dim3(NH, NB), 64, 0, stream>>>(S, SSQ, w_proj, temp, MP);
  k_gemm_out<<<dim3(HW / 128, NB), 256, 0, stream>>>(MP, VT, out);
}